// Round 12
// baseline (285.161 us; speedup 1.0000x reference)
//
#include <hip/hip_runtime.h>
#include <hip/hip_bf16.h>
#include <stdint.h>

#define DIM 128
#define NH 8
#define CH 4096          // edges per bucketing block
#define BK 128           // nodes per bucket (K = ceil(N/128))
#define LS 136           // LDS row stride in shorts: 272B rows -> 16B-aligned b128
#define EBUF 4096        // per-bucket edge staging (mean 2048, sd ~45 for uniform dst)

using bf16 = __hip_bfloat16;
typedef __attribute__((ext_vector_type(8))) short short8;
typedef __attribute__((ext_vector_type(4))) float floatx4;

// head-major permutation: orig dim d -> pos(d) = (d&7)*16 + (d>>3)
// inverse: position kt -> orig(kt) = (kt&15)*8 + (kt>>4)

__device__ inline float bf2f(unsigned short b) {
    return __uint_as_float(((unsigned)b) << 16);
}
__device__ inline unsigned short f2bf(float f) {
    unsigned u = __float_as_uint(f);
    u += 0x7FFFu + ((u >> 16) & 1u);   // RNE
    return (unsigned short)(u >> 16);
}

__device__ inline float gelu_tanh(float x) {
    float x3 = x * x * x;
    float u = 0.7978845608028654f * (x + 0.044715f * x3);
    float e = __expf(2.f * u);
    float t = 1.f - 2.f / (e + 1.f);   // tanh(u), safe at +/-inf
    return 0.5f * x * (1.f + t);
}

// ============ K1: chunk-local bucket sort fused with weight preconv ============
// blocks [0,B): sort chunk b by bucket; write packed (block-exclusive) + lofs[b][k].
// blocks [B,B+12): weight quarters. block B+12: wc.
__launch_bounds__(256)
__global__ void scatter_pre_kernel(const int* __restrict__ src, const int* __restrict__ dst,
                                   int* __restrict__ lofs, unsigned* __restrict__ packed,
                                   int E, int K, int B,
                                   const float* __restrict__ w_in, const float* __restrict__ w1,
                                   const float* __restrict__ w2, const float* __restrict__ w_au,
                                   const float* __restrict__ w_av,
                                   unsigned short* __restrict__ w_in_b, unsigned short* __restrict__ w1_b,
                                   unsigned short* __restrict__ w2_b, unsigned short* __restrict__ wc_b) {
    __shared__ int hist[1024];
    __shared__ int cur[1024];
    __shared__ int wsum[4];
    const int b = blockIdx.x, tid = threadIdx.x;
    if (b < B) {
        for (int k = tid; k < 1024; k += 256) hist[k] = 0;
        __syncthreads();
        const int base = b * CH, end = min(base + CH, E);
        for (int i = base + tid; i < end; i += 256)
            atomicAdd(&hist[dst[i] >> 7], 1);
        __syncthreads();
        int v[4]; int t = 0;
        #pragma unroll
        for (int j = 0; j < 4; ++j) { int x = hist[tid * 4 + j]; v[j] = t; t += x; }
        const int lane = tid & 63, wv = tid >> 6;
        int incl = t;
        #pragma unroll
        for (int off = 1; off < 64; off <<= 1) {
            int y = __shfl_up(incl, off);
            if (lane >= off) incl += y;
        }
        if (lane == 63) wsum[wv] = incl;
        __syncthreads();
        int woff = 0;
        #pragma unroll
        for (int w = 0; w < 4; ++w) if (w < wv) woff += wsum[w];
        int texcl = woff + incl - t;
        #pragma unroll
        for (int j = 0; j < 4; ++j) {
            int k = tid * 4 + j;
            int e = texcl + v[j];
            cur[k] = e;
            if (k < K) lofs[(size_t)b * K + k] = e;   // contiguous per block
        }
        __syncthreads();
        for (int i = base + tid; i < end; i += 256) {
            int d = dst[i], s = src[i];
            int pos = atomicAdd(&cur[d >> 7], 1);
            packed[(size_t)b * CH + pos] = (unsigned)s | ((unsigned)(d & 127) << 20);
        }
    } else {
        int pb = b - B;
        if (pb < 12) {
            const int m = pb >> 2, qtr = pb & 3;
            const float* W = m == 0 ? w_in : (m == 1 ? w1 : w2);
            unsigned short* O = m == 0 ? w_in_b : (m == 1 ? w1_b : w2_b);
            const bool perm = (m == 1);
            #pragma unroll
            for (int i = 0; i < 16; ++i) {
                int o = qtr * 4096 + tid + i * 256;   // o = n*128 + k
                int k = o & 127, n = o >> 7;
                int krow = perm ? ((k & 15) * 8 + (k >> 4)) : k;
                O[o] = f2bf(W[krow * 128 + n]);
            }
        } else {
            #pragma unroll
            for (int i = 0; i < 8; ++i) {
                int o = tid + i * 256;                // o = j*128 + kt
                int j = o >> 7, kt = o & 127;
                int ko = (kt & 15) * 8 + (kt >> 4);
                float v = (j < 8) ? w_au[ko * 8 + j] : w_av[ko * 8 + (j - 8)];
                wc_b[o] = f2bf(v);
            }
        }
    }
}

// vector stage: 2048 short8-groups (128x128 bf16) with 512 threads; all b128, coalesced.
__device__ __forceinline__ void stage_pre(unsigned short* wt, const unsigned short* __restrict__ pre,
                                          int tid) {
    #pragma unroll
    for (int i = 0; i < 4; ++i) {
        int g = tid + i * 512;                    // 0..2047: n = g>>4, blk = g&15
        short8 v = *(const short8*)(pre + g * 8);
        *(short8*)(wt + (g >> 4) * LS + (g & 15) * 8) = v;
    }
}

// ============ K2: h = x@w_in + b_in (head-major bf16) ; au/av via MFMA ============
__launch_bounds__(512)
__global__ void gemm_in_attn_kernel(const float* __restrict__ x, const unsigned short* __restrict__ w_in_b,
                                    const float* __restrict__ b_in,
                                    const unsigned short* __restrict__ wc_b, const float* __restrict__ b_au,
                                    bf16* __restrict__ h, float* __restrict__ au,
                                    float* __restrict__ av, int M) {
    __shared__ __align__(16) unsigned short wt[128 * LS];  // weights; then reused as h tile
    __shared__ __align__(16) unsigned short wc[16 * LS];
    const int tid = threadIdx.x;

    stage_pre(wt, w_in_b, tid);
    {   // wc: 512 x 4 shorts
        int j = tid >> 5, kt4 = (tid & 31) * 4;
        const unsigned* s = (const unsigned*)(wc_b + j * 128 + kt4);
        unsigned* d = (unsigned*)(wc + j * LS + kt4);
        d[0] = s[0]; d[1] = s[1];
    }
    __syncthreads();

    const int wave = tid >> 6;
    const int lane = tid & 63;
    const int l15 = lane & 15;
    const int q = lane >> 4;
    const int rowbase = blockIdx.x * 128 + wave * 16;
    const int rowA = min(rowbase + l15, M - 1);

    floatx4 acc[8];
    #pragma unroll
    for (int c = 0; c < 8; ++c) acc[c] = (floatx4){0.f, 0.f, 0.f, 0.f};

    #pragma unroll
    for (int kk = 0; kk < 4; ++kk) {
        const float* ap = x + (size_t)rowA * 128 + kk * 32 + q * 8;
        floatx4 a0 = *(const floatx4*)ap;
        floatx4 a1 = *(const floatx4*)(ap + 4);
        union { short8 s; unsigned short u[8]; } cv;
        #pragma unroll
        for (int j = 0; j < 4; ++j) { cv.u[j] = f2bf(a0[j]); cv.u[4 + j] = f2bf(a1[j]); }
        short8 afrag = cv.s;
        #pragma unroll
        for (int c = 0; c < 8; ++c) {
            short8 bfrag = *(const short8*)(wt + (c * 16 + l15) * LS + kk * 32 + q * 8);
            acc[c] = __builtin_amdgcn_mfma_f32_16x16x32_bf16(afrag, bfrag, acc[c], 0, 0, 0);
        }
    }
    __syncthreads();   // all wt reads done -> reuse as 128-row h tile

    const int rl0 = wave * 16 + q * 4;     // local row in h tile
    #pragma unroll
    for (int c = 0; c < 8; ++c) {
        int col = c * 16 + l15;
        int colw = (col & 7) * 16 + (col >> 3);   // head-major position
        float b = b_in[col];
        #pragma unroll
        for (int r = 0; r < 4; ++r)
            wt[(rl0 + r) * LS + colw] = f2bf(acc[c][r] + b);
    }
    __syncthreads();

    // coalesced h write from LDS tile (b128)
    const int blk0 = blockIdx.x * 128;
    #pragma unroll
    for (int i = 0; i < 4; ++i) {
        int g = tid + i * 512;                 // row = g>>4, blk = g&15
        int row = g >> 4;
        if (blk0 + row < M) {
            short8 v = *(const short8*)(wt + row * LS + (g & 15) * 8);
            *(short8*)((unsigned short*)h + (size_t)(blk0 + row) * 128 + (g & 15) * 8) = v;
        }
    }

    // au/av: one MFMA chain against wc (own-wave rows of wt)
    floatx4 acc2 = (floatx4){0.f, 0.f, 0.f, 0.f};
    #pragma unroll
    for (int kk = 0; kk < 4; ++kk) {
        short8 af = *(const short8*)(wt + (wave * 16 + l15) * LS + kk * 32 + q * 8);
        short8 bf = *(const short8*)(wc + l15 * LS + kk * 32 + q * 8);
        acc2 = __builtin_amdgcn_mfma_f32_16x16x32_bf16(af, bf, acc2, 0, 0, 0);
    }
    {
        const int row0 = rowbase + q * 4;
        int col = l15;
        #pragma unroll
        for (int r = 0; r < 4; ++r) {
            int rr = row0 + r;
            if (rr < M) {
                if (col < 8) au[(size_t)rr * 8 + col] = acc2[r] + b_au[col];
                else         av[(size_t)rr * 8 + (col - 8)] = acc2[r];
            }
        }
    }
}

// ============ fused FF: out = gelu(A@w1 + b1) @ w2 + b2 (A head-major bf16) ============
__launch_bounds__(512)
__global__ void ff_kernel(const bf16* __restrict__ A, const unsigned short* __restrict__ w1_b,
                          const float* __restrict__ b1, const unsigned short* __restrict__ w2_b,
                          const float* __restrict__ b2, float* __restrict__ out, int M) {
    __shared__ __align__(16) unsigned short wt[128 * LS];
    __shared__ __align__(16) unsigned short ht[128 * LS];
    const int tid = threadIdx.x;

    stage_pre(wt, w1_b, tid);
    __syncthreads();

    const int wave = tid >> 6;
    const int lane = tid & 63;
    const int l15 = lane & 15;
    const int q = lane >> 4;
    const int rowbase = blockIdx.x * 128 + wave * 16;
    const int rowA = min(rowbase + l15, M - 1);

    floatx4 acc[8];
    #pragma unroll
    for (int c = 0; c < 8; ++c) acc[c] = (floatx4){0.f, 0.f, 0.f, 0.f};

    #pragma unroll
    for (int kk = 0; kk < 4; ++kk) {
        short8 afrag = *(const short8*)((const unsigned short*)A + (size_t)rowA * 128 + kk * 32 + q * 8);
        #pragma unroll
        for (int c = 0; c < 8; ++c) {
            short8 bfrag = *(const short8*)(wt + (c * 16 + l15) * LS + kk * 32 + q * 8);
            acc[c] = __builtin_amdgcn_mfma_f32_16x16x32_bf16(afrag, bfrag, acc[c], 0, 0, 0);
        }
    }
    __syncthreads();   // wt reads done

    stage_pre(wt, w2_b, tid);     // re-stage w2 (cheap vector copy)
    const int rl0 = wave * 16 + q * 4;
    #pragma unroll
    for (int c = 0; c < 8; ++c) {
        int col = c * 16 + l15;
        float b = b1[col];
        #pragma unroll
        for (int r = 0; r < 4; ++r)
            ht[(rl0 + r) * LS + col] = f2bf(gelu_tanh(acc[c][r] + b));
    }
    __syncthreads();

    floatx4 acc2[8];
    #pragma unroll
    for (int c = 0; c < 8; ++c) acc2[c] = (floatx4){0.f, 0.f, 0.f, 0.f};
    #pragma unroll
    for (int kk = 0; kk < 4; ++kk) {
        short8 af = *(const short8*)(ht + (wave * 16 + l15) * LS + kk * 32 + q * 8);
        #pragma unroll
        for (int c = 0; c < 8; ++c) {
            short8 bfrag = *(const short8*)(wt + (c * 16 + l15) * LS + kk * 32 + q * 8);
            acc2[c] = __builtin_amdgcn_mfma_f32_16x16x32_bf16(af, bfrag, acc2[c], 0, 0, 0);
        }
    }

    const int row0 = rowbase + q * 4;
    #pragma unroll
    for (int c = 0; c < 8; ++c) {
        int col = c * 16 + l15;
        float b = b2[col];
        #pragma unroll
        for (int r = 0; r < 4; ++r) {
            int rr = row0 + r;
            if (rr < M) out[(size_t)rr * 128 + col] = acc2[c][r] + b;
        }
    }
}

// ============ K3: fused CSR-finalize + softmax aggregation (one block per bucket) ============
// 512 threads / 8 waves. Phases: (1) in-block scan of run lengths from lofs; (2) gather
// runs into LDS ebuf; (3) node hist+scan; (4) group into ebuf2; (5) each wave aggregates
// 16 nodes, edge src from LDS, agg written directly. No esrc/rowptr/deg materialization.

__device__ __forceinline__ void unpack8fma(uint4 w, float p, float* o) {
    o[0] = fmaf(p, __uint_as_float(w.x << 16), o[0]);
    o[1] = fmaf(p, __uint_as_float(w.x & 0xFFFF0000u), o[1]);
    o[2] = fmaf(p, __uint_as_float(w.y << 16), o[2]);
    o[3] = fmaf(p, __uint_as_float(w.y & 0xFFFF0000u), o[3]);
    o[4] = fmaf(p, __uint_as_float(w.z << 16), o[4]);
    o[5] = fmaf(p, __uint_as_float(w.z & 0xFFFF0000u), o[5]);
    o[6] = fmaf(p, __uint_as_float(w.w << 16), o[6]);
    o[7] = fmaf(p, __uint_as_float(w.w & 0xFFFF0000u), o[7]);
}

template <bool MASKED>
__device__ __forceinline__ void do8e_lds(const unsigned* ep, int i, int nd,
                                         int e, int head, int d0b,
                                         const float* __restrict__ au,
                                         const char* __restrict__ hpb,
                                         float avh, float& l, float* o) {
    int idx = i + e;
    int s;
    float m = 1.f;
    if constexpr (MASKED) {
        s = (int)ep[min(idx, nd - 1)];
        m = idx < nd ? 1.f : 0.f;
    } else {
        s = (int)ep[idx];
    }
    float a = au[(s << 3) + head];
    size_t off = ((size_t)(unsigned)s) << 8;        // 256 B per node row
    uint4 w0 = *(const uint4*)(hpb + off + d0b);
    uint4 w1 = *(const uint4*)(hpb + off + d0b + 16);
    float x = a + avh;
    x = fmaxf(x, 0.2f * x);          // LeakyReLU(0.2)
    float p = __expf(x);
    if constexpr (MASKED) p *= m;
    l += p;
    unpack8fma(w0, p, o);
    unpack8fma(w1, p, o + 8);
}

__launch_bounds__(512)
__global__ void csr_agg_kernel(const unsigned* __restrict__ packed, const int* __restrict__ lofs,
                               const float* __restrict__ au, const float* __restrict__ av,
                               const bf16* __restrict__ h, bf16* __restrict__ agg,
                               int N, int E, int K, int B) {
    __shared__ unsigned ebuf[EBUF];     // 16 KB: bucket edges, chunk order
    __shared__ unsigned ebuf2[EBUF];    // 16 KB: bucket edges, grouped by node
    __shared__ int dsc[512];            // per-chunk dest base within ebuf (B<=512)
    __shared__ int hist[128], cur[128], rpl[128];
    __shared__ int wsum[8];
    __shared__ int wtot;
    const int k = blockIdx.x, tid = threadIdx.x;
    const int lane = tid & 63, wv = tid >> 6;

    // ---- phase 1: scan run lengths -> dsc[b], cnt ----
    int lo = 0, hi = 0;
    if (tid < B) {
        lo = lofs[(size_t)tid * K + k];
        int chunk_len = min(CH, E - tid * CH);
        hi = (k + 1 < K) ? lofs[(size_t)tid * K + (k + 1)] : chunk_len;
    }
    int len = hi - lo;
    if (tid < 128) hist[tid] = 0;
    int incl = len;
    #pragma unroll
    for (int off = 1; off < 64; off <<= 1) {
        int y = __shfl_up(incl, off);
        if (lane >= off) incl += y;
    }
    if (lane == 63) wsum[wv] = incl;
    __syncthreads();
    int woff = 0, cnt = 0;
    #pragma unroll
    for (int w = 0; w < 8; ++w) { int s = wsum[w]; if (w < wv) woff += s; cnt += s; }
    if (tid < B) dsc[tid] = woff + incl - len;
    __syncthreads();

    // ---- phase 2: gather runs into ebuf ----
    for (int b = tid; b < B; b += 512) {
        int blo = lofs[(size_t)b * K + k];
        int chunk_len = min(CH, E - b * CH);
        int bhi = (k + 1 < K) ? lofs[(size_t)b * K + (k + 1)] : chunk_len;
        int dbase = dsc[b];
        const unsigned* sp = packed + (size_t)b * CH;
        for (int j = blo; j < bhi; ++j) ebuf[dbase + (j - blo)] = sp[j];
    }
    __syncthreads();

    // ---- phase 3: per-node hist + scan ----
    for (int i = tid; i < cnt; i += 512)
        atomicAdd(&hist[ebuf[i] >> 20], 1);
    __syncthreads();

    int v = (tid < 128) ? hist[tid] : 0;
    int incl2 = v;
    #pragma unroll
    for (int off = 1; off < 64; off <<= 1) {
        int y = __shfl_up(incl2, off);
        if (lane >= off) incl2 += y;
    }
    if (tid == 63) wtot = incl2;       // total of nodes 0..63
    __syncthreads();
    int excl = incl2 - v + ((tid >= 64 && tid < 128) ? wtot : 0);
    if (tid < 128) { rpl[tid] = excl; cur[tid] = excl; }
    __syncthreads();

    // ---- phase 4: group into ebuf2 (src only) ----
    for (int i = tid; i < cnt; i += 512) {
        unsigned p = ebuf[i];
        int pos = atomicAdd(&cur[p >> 20], 1);
        ebuf2[pos] = p & 0xFFFFFu;
    }
    __syncthreads();

    // ---- phase 5: aggregation, 16 nodes per wave ----
    const int e = lane >> 3;          // which edge of the 8-batch
    const int head = lane & 7;        // lane's single head
    const int d0b = head * 32;        // byte offset of its 16 head-major dims
    const char* hpb = (const char*)h;

    for (int t = 0; t < 16; ++t) {
        int nl = wv * 16 + t;
        int node = k * BK + nl;
        if (node >= N) break;
        const int nd = hist[nl];
        const unsigned* ep = ebuf2 + rpl[nl];
        const float avh = av[((size_t)node << 3) + head];

        float l0 = 0.f;
        float o[16];
        #pragma unroll
        for (int j = 0; j < 16; ++j) o[j] = 0.f;

        int i = 0;
        for (; i + 16 <= nd; i += 16) {
            do8e_lds<false>(ep, i, nd, e, head, d0b, au, hpb, avh, l0, o);
            do8e_lds<false>(ep, i + 8, nd, e, head, d0b, au, hpb, avh, l0, o);
        }
        if (i + 8 <= nd) { do8e_lds<false>(ep, i, nd, e, head, d0b, au, hpb, avh, l0, o); i += 8; }
        if (i < nd) do8e_lds<true>(ep, i, nd, e, head, d0b, au, hpb, avh, l0, o);

        #pragma unroll
        for (int j = 0; j < 16; ++j) {
            o[j] += __shfl_xor(o[j], 8);
            o[j] += __shfl_xor(o[j], 16);
            o[j] += __shfl_xor(o[j], 32);
        }
        l0 += __shfl_xor(l0, 8);
        l0 += __shfl_xor(l0, 16);
        l0 += __shfl_xor(l0, 32);

        if (lane < 8) {
            float inv = l0 > 0.f ? 1.f / l0 : 0.f;   // deg-0 -> 0 (matches segment_sum)
            unsigned r[8];
            #pragma unroll
            for (int j = 0; j < 8; ++j)
                r[j] = ((unsigned)f2bf(o[2 * j + 1] * inv) << 16) | (unsigned)f2bf(o[2 * j] * inv);
            char* outp = (char*)agg + ((size_t)node << 8) + lane * 32;
            *(uint4*)outp = (uint4){r[0], r[1], r[2], r[3]};
            *(uint4*)(outp + 16) = (uint4){r[4], r[5], r[6], r[7]};
        }
    }
}

extern "C" void kernel_launch(void* const* d_in, const int* in_sizes, int n_in,
                              void* d_out, int out_size, void* d_ws, size_t ws_size,
                              hipStream_t stream) {
    const float* x    = (const float*)d_in[0];
    const int*   src  = (const int*)d_in[1];
    const int*   dst  = (const int*)d_in[2];
    const float* w_in = (const float*)d_in[3];
    const float* b_in = (const float*)d_in[4];
    const float* w_au = (const float*)d_in[5];
    const float* b_au = (const float*)d_in[6];
    const float* w_av = (const float*)d_in[7];
    const float* w1   = (const float*)d_in[8];
    const float* b1   = (const float*)d_in[9];
    const float* w2   = (const float*)d_in[10];
    const float* b2   = (const float*)d_in[11];
    const int N = in_sizes[0] / DIM;
    const int E = in_sizes[1];
    const int K = (N + BK - 1) / BK;      // buckets
    const int B = (E + CH - 1) / CH;      // bucketing blocks (<=512 for E<=2M)

    // workspace ~65.3 MB, NO overlays (csr_agg reads packed/lofs while writing agg)
    char* p = (char*)d_ws;
    bf16* h      = (bf16*)p; p += (size_t)N * DIM * 2;    // 25.6 MB head-major
    float* au    = (float*)p; p += (size_t)N * NH * 4;    //  3.2 MB
    float* av    = (float*)p; p += (size_t)N * NH * 4;    //  3.2 MB
    bf16* agg    = (bf16*)p; p += (size_t)N * DIM * 2;    // 25.6 MB head-major
    unsigned* packed = (unsigned*)p; p += (size_t)B * CH * 4;          // 6.4 MB
    int* lofs  = (int*)p; p += (size_t)B * K * 4;                      // 1.25 MB
    unsigned short* w_in_b = (unsigned short*)p; p += 128 * 128 * 2;   // 32 KB bf16 wt-layout
    unsigned short* w1_b   = (unsigned short*)p; p += 128 * 128 * 2;   // 32 KB (PERM applied)
    unsigned short* w2_b   = (unsigned short*)p; p += 128 * 128 * 2;   // 32 KB
    unsigned short* wc_b   = (unsigned short*)p; p += 16 * 128 * 2;    //  4 KB (PERM applied)

    const int row_blocks = (N + 127) / 128;

    scatter_pre_kernel<<<B + 13, 256, 0, stream>>>(src, dst, lofs, packed,
                                                   E, K, B, w_in, w1, w2, w_au, w_av,
                                                   w_in_b, w1_b, w2_b, wc_b);

    gemm_in_attn_kernel<<<row_blocks, 512, 0, stream>>>(x, w_in_b, b_in, wc_b, b_au,
                                                        h, au, av, N);

    csr_agg_kernel<<<K, 512, 0, stream>>>(packed, lofs, au, av, h, agg, N, E, K, B);

    ff_kernel<<<row_blocks, 512, 0, stream>>>(agg, w1_b, b1, w2_b, b2, (float*)d_out, N);
}

// Round 13
// 261.647 us; speedup vs baseline: 1.0899x; 1.0899x over previous
//
#include <hip/hip_runtime.h>
#include <hip/hip_bf16.h>
#include <stdint.h>

#define DIM 128
#define NH 8
#define CH 4096          // edges per bucketing block
#define BK 128           // nodes per bucket (K = ceil(N/128))
#define LS 136           // LDS row stride in shorts: 272B rows -> 16B-aligned b128
#define EBUF 4096        // per-bucket edge staging (mean 2048 for uniform dst)
#define SMEM_BYTES 39936 // union: gia 39168, bcsr ~36.4K; 4 blocks/CU

using bf16 = __hip_bfloat16;
typedef __attribute__((ext_vector_type(8))) short short8;
typedef __attribute__((ext_vector_type(4))) float floatx4;

// head-major permutation: orig dim d -> pos(d) = (d&7)*16 + (d>>3)
// inverse: position kt -> orig(kt) = (kt&15)*8 + (kt>>4)

__device__ inline float bf2f(unsigned short b) {
    return __uint_as_float(((unsigned)b) << 16);
}
__device__ inline unsigned short f2bf(float f) {
    unsigned u = __float_as_uint(f);
    u += 0x7FFFu + ((u >> 16) & 1u);   // RNE
    return (unsigned short)(u >> 16);
}

__device__ inline float gelu_tanh(float x) {
    float x3 = x * x * x;
    float u = 0.7978845608028654f * (x + 0.044715f * x3);
    float e = __expf(2.f * u);
    float t = 1.f - 2.f / (e + 1.f);   // tanh(u), safe at +/-inf
    return 0.5f * x * (1.f + t);
}

// ============ K1: chunk-local bucket sort fused with weight preconv ============
// blocks [0,B): sort chunk b by bucket; write packed (block-exclusive) + lofs[b][k].
// blocks [B,B+12): weight quarters. block B+12: wc + total=0.
__launch_bounds__(256)
__global__ void scatter_pre_kernel(const int* __restrict__ src, const int* __restrict__ dst,
                                   int* __restrict__ lofs, unsigned* __restrict__ packed,
                                   int* __restrict__ total, int E, int K, int B,
                                   const float* __restrict__ w_in, const float* __restrict__ w1,
                                   const float* __restrict__ w2, const float* __restrict__ w_au,
                                   const float* __restrict__ w_av,
                                   unsigned short* __restrict__ w_in_b, unsigned short* __restrict__ w1_b,
                                   unsigned short* __restrict__ w2_b, unsigned short* __restrict__ wc_b) {
    __shared__ int hist[1024];
    __shared__ int cur[1024];
    __shared__ int wsum[4];
    const int b = blockIdx.x, tid = threadIdx.x;
    if (b < B) {
        for (int k = tid; k < 1024; k += 256) hist[k] = 0;
        __syncthreads();
        const int base = b * CH, end = min(base + CH, E);
        for (int i = base + tid; i < end; i += 256)
            atomicAdd(&hist[dst[i] >> 7], 1);
        __syncthreads();
        int v[4]; int t = 0;
        #pragma unroll
        for (int j = 0; j < 4; ++j) { int x = hist[tid * 4 + j]; v[j] = t; t += x; }
        const int lane = tid & 63, wv = tid >> 6;
        int incl = t;
        #pragma unroll
        for (int off = 1; off < 64; off <<= 1) {
            int y = __shfl_up(incl, off);
            if (lane >= off) incl += y;
        }
        if (lane == 63) wsum[wv] = incl;
        __syncthreads();
        int woff = 0;
        #pragma unroll
        for (int w = 0; w < 4; ++w) if (w < wv) woff += wsum[w];
        int texcl = woff + incl - t;
        #pragma unroll
        for (int j = 0; j < 4; ++j) {
            int k = tid * 4 + j;
            int e = texcl + v[j];
            cur[k] = e;
            if (k < K) lofs[(size_t)b * K + k] = e;   // contiguous per block
        }
        __syncthreads();
        for (int i = base + tid; i < end; i += 256) {
            int d = dst[i], s = src[i];
            int pos = atomicAdd(&cur[d >> 7], 1);
            packed[(size_t)b * CH + pos] = (unsigned)s | ((unsigned)(d & 127) << 20);
        }
    } else {
        int pb = b - B;
        if (pb < 12) {
            const int m = pb >> 2, qtr = pb & 3;
            const float* W = m == 0 ? w_in : (m == 1 ? w1 : w2);
            unsigned short* O = m == 0 ? w_in_b : (m == 1 ? w1_b : w2_b);
            const bool perm = (m == 1);
            #pragma unroll
            for (int i = 0; i < 16; ++i) {
                int o = qtr * 4096 + tid + i * 256;   // o = n*128 + k
                int k = o & 127, n = o >> 7;
                int krow = perm ? ((k & 15) * 8 + (k >> 4)) : k;
                O[o] = f2bf(W[krow * 128 + n]);
            }
        } else {
            #pragma unroll
            for (int i = 0; i < 8; ++i) {
                int o = tid + i * 256;                // o = j*128 + kt
                int j = o >> 7, kt = o & 127;
                int ko = (kt & 15) * 8 + (kt >> 4);
                float v = (j < 8) ? w_au[ko * 8 + j] : w_av[ko * 8 + (j - 8)];
                wc_b[o] = f2bf(v);
            }
            if (tid == 0) total[0] = 0;
        }
    }
}

// vector stage: 2048 short8-groups (128x128 bf16) with 512 threads; all b128, coalesced.
__device__ __forceinline__ void stage_pre(unsigned short* wt, const unsigned short* __restrict__ pre,
                                          int tid) {
    #pragma unroll
    for (int i = 0; i < 4; ++i) {
        int g = tid + i * 512;                    // 0..2047: n = g>>4, blk = g&15
        short8 v = *(const short8*)(pre + g * 8);
        *(short8*)(wt + (g >> 4) * LS + (g & 15) * 8) = v;
    }
}

// ============ K2: gia (blocks [0,RB)) || bucket-CSR finalize (blocks [RB,RB+K)) ============
// Both depend only on K1; independent of each other -> block-range fusion, bcsr hides
// behind gia. Shared-memory UNION via one byte carve (39.9 KB -> 4 blocks/CU both ways).
__launch_bounds__(512)
__global__ void gia_bcsr_kernel(const float* __restrict__ x, const unsigned short* __restrict__ w_in_b,
                                const float* __restrict__ b_in,
                                const unsigned short* __restrict__ wc_b, const float* __restrict__ b_au,
                                bf16* __restrict__ h, float* __restrict__ au,
                                float* __restrict__ av, int M, int RB,
                                const unsigned* __restrict__ packed, const int* __restrict__ lofs,
                                int* __restrict__ total, int* __restrict__ rowptr,
                                int* __restrict__ deg, int* __restrict__ esrc,
                                int N, int E, int K, int B) {
    __shared__ __align__(16) char smem[SMEM_BYTES];
    const int tid = threadIdx.x;
    const int lane = tid & 63, wv = tid >> 6;

    if ((int)blockIdx.x >= RB) {
        // ---- bucket-CSR branch (512 threads, r12-verified phases) ----
        unsigned* ebuf  = (unsigned*)smem;            // 16 KB
        unsigned* ebuf2 = ebuf + EBUF;                // 16 KB
        int* dsc  = (int*)(ebuf2 + EBUF);             // 2 KB
        int* hist = dsc + 512;                        // 512 B
        int* cur  = hist + 128;
        int* rpl  = cur + 128;
        int* wsum = rpl + 128;                        // 8
        int* scal = wsum + 8;                         // [0]=wtot [1]=start
        const int k = blockIdx.x - RB;

        // phase 1: scan run lengths -> dsc, cnt; allocate start
        int lo = 0, hi = 0;
        if (tid < B) {
            lo = lofs[(size_t)tid * K + k];
            int chunk_len = min(CH, E - tid * CH);
            hi = (k + 1 < K) ? lofs[(size_t)tid * K + (k + 1)] : chunk_len;
        }
        int len = hi - lo;
        if (tid < 128) hist[tid] = 0;
        int incl = len;
        #pragma unroll
        for (int off = 1; off < 64; off <<= 1) {
            int y = __shfl_up(incl, off);
            if (lane >= off) incl += y;
        }
        if (lane == 63) wsum[wv] = incl;
        __syncthreads();
        int woff = 0, cnt = 0;
        #pragma unroll
        for (int w = 0; w < 8; ++w) { int s = wsum[w]; if (w < wv) woff += s; cnt += s; }
        if (tid < B) dsc[tid] = woff + incl - len;
        if (tid == 0) scal[1] = atomicAdd(total, cnt);
        __syncthreads();
        const int start = scal[1];

        // phase 2: gather runs into ebuf
        for (int b = tid; b < B; b += 512) {
            int blo = lofs[(size_t)b * K + k];
            int chunk_len = min(CH, E - b * CH);
            int bhi = (k + 1 < K) ? lofs[(size_t)b * K + (k + 1)] : chunk_len;
            int dbase = dsc[b];
            const unsigned* sp = packed + (size_t)b * CH;
            for (int j = blo; j < bhi; ++j) ebuf[dbase + (j - blo)] = sp[j];
        }
        __syncthreads();

        // phase 3: per-node hist + scan
        for (int i = tid; i < cnt; i += 512)
            atomicAdd(&hist[ebuf[i] >> 20], 1);
        __syncthreads();
        int v = (tid < 128) ? hist[tid] : 0;
        int incl2 = v;
        #pragma unroll
        for (int off = 1; off < 64; off <<= 1) {
            int y = __shfl_up(incl2, off);
            if (lane >= off) incl2 += y;
        }
        if (tid == 63) scal[0] = incl2;      // total of nodes 0..63
        __syncthreads();
        int excl = incl2 - v + ((tid >= 64 && tid < 128) ? scal[0] : 0);
        if (tid < 128) { rpl[tid] = excl; cur[tid] = excl; }
        __syncthreads();

        // phase 4: group into ebuf2 (src only)
        for (int i = tid; i < cnt; i += 512) {
            unsigned p = ebuf[i];
            int pos = atomicAdd(&cur[p >> 20], 1);
            ebuf2[pos] = p & 0xFFFFFu;
        }
        __syncthreads();

        // phase 5: coalesced global writes
        for (int i = tid; i < cnt; i += 512) esrc[start + i] = (int)ebuf2[i];
        if (tid < 128) {
            int n = k * BK + tid;
            if (n < N) { rowptr[n] = start + rpl[tid]; deg[n] = hist[tid]; }
        }
        return;
    }

    // ---- gemm_in_attn branch ----
    unsigned short* wt = (unsigned short*)smem;            // 34816 B; reused as h tile
    unsigned short* wc = (unsigned short*)(smem + 34816);  //  4352 B

    stage_pre(wt, w_in_b, tid);
    {   // wc: 512 x 4 shorts
        int j = tid >> 5, kt4 = (tid & 31) * 4;
        const unsigned* s = (const unsigned*)(wc_b + j * 128 + kt4);
        unsigned* d = (unsigned*)(wc + j * LS + kt4);
        d[0] = s[0]; d[1] = s[1];
    }
    __syncthreads();

    const int l15 = lane & 15;
    const int q = lane >> 4;
    const int rowbase = blockIdx.x * 128 + wv * 16;
    const int rowA = min(rowbase + l15, M - 1);

    floatx4 acc[8];
    #pragma unroll
    for (int c = 0; c < 8; ++c) acc[c] = (floatx4){0.f, 0.f, 0.f, 0.f};

    #pragma unroll
    for (int kk = 0; kk < 4; ++kk) {
        const float* ap = x + (size_t)rowA * 128 + kk * 32 + q * 8;
        floatx4 a0 = *(const floatx4*)ap;
        floatx4 a1 = *(const floatx4*)(ap + 4);
        union { short8 s; unsigned short u[8]; } cv;
        #pragma unroll
        for (int j = 0; j < 4; ++j) { cv.u[j] = f2bf(a0[j]); cv.u[4 + j] = f2bf(a1[j]); }
        short8 afrag = cv.s;
        #pragma unroll
        for (int c = 0; c < 8; ++c) {
            short8 bfrag = *(const short8*)(wt + (c * 16 + l15) * LS + kk * 32 + q * 8);
            acc[c] = __builtin_amdgcn_mfma_f32_16x16x32_bf16(afrag, bfrag, acc[c], 0, 0, 0);
        }
    }
    __syncthreads();   // all wt reads done -> reuse as 128-row h tile

    const int rl0 = wv * 16 + q * 4;     // local row in h tile
    #pragma unroll
    for (int c = 0; c < 8; ++c) {
        int col = c * 16 + l15;
        int colw = (col & 7) * 16 + (col >> 3);   // head-major position
        float b = b_in[col];
        #pragma unroll
        for (int r = 0; r < 4; ++r)
            wt[(rl0 + r) * LS + colw] = f2bf(acc[c][r] + b);
    }
    __syncthreads();

    // coalesced h write from LDS tile (b128)
    const int blk0 = blockIdx.x * 128;
    #pragma unroll
    for (int i = 0; i < 4; ++i) {
        int g = tid + i * 512;                 // row = g>>4, blk = g&15
        int row = g >> 4;
        if (blk0 + row < M) {
            short8 v = *(const short8*)(wt + row * LS + (g & 15) * 8);
            *(short8*)((unsigned short*)h + (size_t)(blk0 + row) * 128 + (g & 15) * 8) = v;
        }
    }

    // au/av: one MFMA chain against wc (own-wave rows of wt)
    floatx4 acc2 = (floatx4){0.f, 0.f, 0.f, 0.f};
    #pragma unroll
    for (int kk = 0; kk < 4; ++kk) {
        short8 af = *(const short8*)(wt + (wv * 16 + l15) * LS + kk * 32 + q * 8);
        short8 bf = *(const short8*)(wc + l15 * LS + kk * 32 + q * 8);
        acc2 = __builtin_amdgcn_mfma_f32_16x16x32_bf16(af, bf, acc2, 0, 0, 0);
    }
    {
        const int row0 = rowbase + q * 4;
        int col = l15;
        #pragma unroll
        for (int r = 0; r < 4; ++r) {
            int rr = row0 + r;
            if (rr < M) {
                if (col < 8) au[(size_t)rr * 8 + col] = acc2[r] + b_au[col];
                else         av[(size_t)rr * 8 + (col - 8)] = acc2[r];
            }
        }
    }
}

// ============ fused FF: out = gelu(A@w1 + b1) @ w2 + b2 (A head-major bf16) ============
__launch_bounds__(512)
__global__ void ff_kernel(const bf16* __restrict__ A, const unsigned short* __restrict__ w1_b,
                          const float* __restrict__ b1, const unsigned short* __restrict__ w2_b,
                          const float* __restrict__ b2, float* __restrict__ out, int M) {
    __shared__ __align__(16) unsigned short wt[128 * LS];
    __shared__ __align__(16) unsigned short ht[128 * LS];
    const int tid = threadIdx.x;

    stage_pre(wt, w1_b, tid);
    __syncthreads();

    const int wave = tid >> 6;
    const int lane = tid & 63;
    const int l15 = lane & 15;
    const int q = lane >> 4;
    const int rowbase = blockIdx.x * 128 + wave * 16;
    const int rowA = min(rowbase + l15, M - 1);

    floatx4 acc[8];
    #pragma unroll
    for (int c = 0; c < 8; ++c) acc[c] = (floatx4){0.f, 0.f, 0.f, 0.f};

    #pragma unroll
    for (int kk = 0; kk < 4; ++kk) {
        short8 afrag = *(const short8*)((const unsigned short*)A + (size_t)rowA * 128 + kk * 32 + q * 8);
        #pragma unroll
        for (int c = 0; c < 8; ++c) {
            short8 bfrag = *(const short8*)(wt + (c * 16 + l15) * LS + kk * 32 + q * 8);
            acc[c] = __builtin_amdgcn_mfma_f32_16x16x32_bf16(afrag, bfrag, acc[c], 0, 0, 0);
        }
    }
    __syncthreads();   // wt reads done

    stage_pre(wt, w2_b, tid);     // re-stage w2 (cheap vector copy)
    const int rl0 = wave * 16 + q * 4;
    #pragma unroll
    for (int c = 0; c < 8; ++c) {
        int col = c * 16 + l15;
        float b = b1[col];
        #pragma unroll
        for (int r = 0; r < 4; ++r)
            ht[(rl0 + r) * LS + col] = f2bf(gelu_tanh(acc[c][r] + b));
    }
    __syncthreads();

    floatx4 acc2[8];
    #pragma unroll
    for (int c = 0; c < 8; ++c) acc2[c] = (floatx4){0.f, 0.f, 0.f, 0.f};
    #pragma unroll
    for (int kk = 0; kk < 4; ++kk) {
        short8 af = *(const short8*)(ht + (wave * 16 + l15) * LS + kk * 32 + q * 8);
        #pragma unroll
        for (int c = 0; c < 8; ++c) {
            short8 bfrag = *(const short8*)(wt + (c * 16 + l15) * LS + kk * 32 + q * 8);
            acc2[c] = __builtin_amdgcn_mfma_f32_16x16x32_bf16(af, bfrag, acc2[c], 0, 0, 0);
        }
    }

    const int row0 = rowbase + q * 4;
    #pragma unroll
    for (int c = 0; c < 8; ++c) {
        int col = c * 16 + l15;
        float b = b2[col];
        #pragma unroll
        for (int r = 0; r < 4; ++r) {
            int rr = row0 + r;
            if (rr < M) out[(size_t)rr * 128 + col] = acc2[c][r] + b;
        }
    }
}

// ======================= K3: fused softmax aggregation (CSR, head-major) =======================
// One wave per node (100K waves -> max TLP for the latency-bound gather), 8 edges in
// flight: 8 lanes per edge, lane owns ONE full head (16 contiguous head-major dims,
// 2 x b128 loads). No max-subtraction: scores bounded ~|8| -> exp <= ~3e3, safe.

__device__ __forceinline__ void unpack8fma(uint4 w, float p, float* o) {
    o[0] = fmaf(p, __uint_as_float(w.x << 16), o[0]);
    o[1] = fmaf(p, __uint_as_float(w.x & 0xFFFF0000u), o[1]);
    o[2] = fmaf(p, __uint_as_float(w.y << 16), o[2]);
    o[3] = fmaf(p, __uint_as_float(w.y & 0xFFFF0000u), o[3]);
    o[4] = fmaf(p, __uint_as_float(w.z << 16), o[4]);
    o[5] = fmaf(p, __uint_as_float(w.z & 0xFFFF0000u), o[5]);
    o[6] = fmaf(p, __uint_as_float(w.w << 16), o[6]);
    o[7] = fmaf(p, __uint_as_float(w.w & 0xFFFF0000u), o[7]);
}

template <bool MASKED>
__device__ __forceinline__ void do8e(const int* __restrict__ ep, int i, int nd,
                                     int e, int head, int d0b,
                                     const float* __restrict__ au,
                                     const char* __restrict__ hpb,
                                     float avh, float& l, float* o) {
    int idx = i + e;
    int s;
    float m = 1.f;
    if constexpr (MASKED) {
        s = ep[min(idx, nd - 1)];
        m = idx < nd ? 1.f : 0.f;
    } else {
        s = ep[idx];
    }
    float a = au[(s << 3) + head];
    size_t off = ((size_t)(unsigned)s) << 8;        // 256 B per node row
    uint4 w0 = *(const uint4*)(hpb + off + d0b);
    uint4 w1 = *(const uint4*)(hpb + off + d0b + 16);
    float x = a + avh;
    x = fmaxf(x, 0.2f * x);          // LeakyReLU(0.2)
    float p = __expf(x);
    if constexpr (MASKED) p *= m;
    l += p;
    unpack8fma(w0, p, o);
    unpack8fma(w1, p, o + 8);
}

__launch_bounds__(256)
__global__ void agg_csr_kernel(const int* __restrict__ rowptr, const int* __restrict__ deg,
                               const int* __restrict__ esrc,
                               const float* __restrict__ au, const float* __restrict__ av,
                               const bf16* __restrict__ h, bf16* __restrict__ agg, int N) {
    const int node = (blockIdx.x * 256 + threadIdx.x) >> 6;
    if (node >= N) return;
    const int lane = threadIdx.x & 63;
    const int e = lane >> 3;          // which edge of the 8-batch
    const int head = lane & 7;        // lane's single head
    const int d0b = head * 32;        // byte offset of its 16 head-major dims
    const char* hpb = (const char*)h;
    const int nd = deg[node];
    const int start = rowptr[node];
    const float avh = av[((size_t)node << 3) + head];
    const int* ep = esrc + start;

    float l0 = 0.f;
    float o[16];
    #pragma unroll
    for (int j = 0; j < 16; ++j) o[j] = 0.f;

    int i = 0;
    for (; i + 16 <= nd; i += 16) {
        do8e<false>(ep, i, nd, e, head, d0b, au, hpb, avh, l0, o);
        do8e<false>(ep, i + 8, nd, e, head, d0b, au, hpb, avh, l0, o);
    }
    if (i + 8 <= nd) { do8e<false>(ep, i, nd, e, head, d0b, au, hpb, avh, l0, o); i += 8; }
    if (i < nd) do8e<true>(ep, i, nd, e, head, d0b, au, hpb, avh, l0, o);

    // sum the 8 edge-groups (lanes l, l^8, l^16, ..., l^56 own the same dims)
    #pragma unroll
    for (int j = 0; j < 16; ++j) {
        o[j] += __shfl_xor(o[j], 8);
        o[j] += __shfl_xor(o[j], 16);
        o[j] += __shfl_xor(o[j], 32);
    }
    l0 += __shfl_xor(l0, 8);
    l0 += __shfl_xor(l0, 16);
    l0 += __shfl_xor(l0, 32);

    if (lane < 8) {
        float inv = l0 > 0.f ? 1.f / l0 : 0.f;   // deg-0 -> 0 (matches segment_sum)
        unsigned r[8];
        #pragma unroll
        for (int j = 0; j < 8; ++j)
            r[j] = ((unsigned)f2bf(o[2 * j + 1] * inv) << 16) | (unsigned)f2bf(o[2 * j] * inv);
        char* outp = (char*)agg + ((size_t)node << 8) + lane * 32;
        *(uint4*)outp = (uint4){r[0], r[1], r[2], r[3]};
        *(uint4*)(outp + 16) = (uint4){r[4], r[5], r[6], r[7]};
    }
}

extern "C" void kernel_launch(void* const* d_in, const int* in_sizes, int n_in,
                              void* d_out, int out_size, void* d_ws, size_t ws_size,
                              hipStream_t stream) {
    const float* x    = (const float*)d_in[0];
    const int*   src  = (const int*)d_in[1];
    const int*   dst  = (const int*)d_in[2];
    const float* w_in = (const float*)d_in[3];
    const float* b_in = (const float*)d_in[4];
    const float* w_au = (const float*)d_in[5];
    const float* b_au = (const float*)d_in[6];
    const float* w_av = (const float*)d_in[7];
    const float* w1   = (const float*)d_in[8];
    const float* b1   = (const float*)d_in[9];
    const float* w2   = (const float*)d_in[10];
    const float* b2   = (const float*)d_in[11];
    const int N = in_sizes[0] / DIM;
    const int E = in_sizes[1];
    const int K = (N + BK - 1) / BK;      // buckets
    const int B = (E + CH - 1) / CH;      // bucketing blocks (<=512 for E<=2M)

    // workspace ~65 MB; packed/lofs overlaid into agg (dead before K3 writes agg)
    char* p = (char*)d_ws;
    int*  deg    = (int*)p;  p += (size_t)N * 4;          //  0.4 MB
    int*  rowptr = (int*)p;  p += (size_t)N * 4;          //  0.4 MB
    int*  esrc   = (int*)p;  p += (size_t)E * 4;          //  6.4 MB
    bf16* h      = (bf16*)p; p += (size_t)N * DIM * 2;    // 25.6 MB head-major
    float* au    = (float*)p; p += (size_t)N * NH * 4;    //  3.2 MB
    float* av    = (float*)p; p += (size_t)N * NH * 4;    //  3.2 MB
    unsigned short* w_in_b = (unsigned short*)p; p += 128 * 128 * 2;   // 32 KB bf16 wt-layout
    unsigned short* w1_b   = (unsigned short*)p; p += 128 * 128 * 2;   // 32 KB (PERM applied)
    unsigned short* w2_b   = (unsigned short*)p; p += 128 * 128 * 2;   // 32 KB
    unsigned short* wc_b   = (unsigned short*)p; p += 16 * 128 * 2;    //  4 KB (PERM applied)
    int* total = (int*)p; p += 64;                                     //  alloc counter
    bf16* agg    = (bf16*)p;  p += (size_t)N * DIM * 2;   // 25.6 MB head-major
    // build-time scratch overlaid into agg (dead until agg_csr runs):
    unsigned* packed = (unsigned*)agg;                          // B*CH*4 ~ 6.4 MB
    int* lofs  = (int*)((char*)agg + (size_t)B * CH * 4);       // B*K*4 ~ 1.25 MB

    const int row_blocks = (N + 127) / 128;

    scatter_pre_kernel<<<B + 13, 256, 0, stream>>>(src, dst, lofs, packed, total,
                                                   E, K, B, w_in, w1, w2, w_au, w_av,
                                                   w_in_b, w1_b, w2_b, wc_b);

    gia_bcsr_kernel<<<row_blocks + K, 512, 0, stream>>>(x, w_in_b, b_in, wc_b, b_au,
                                                        h, au, av, N, row_blocks,
                                                        packed, lofs, total,
                                                        rowptr, deg, esrc, N, E, K, B);

    agg_csr_kernel<<<(N + 3) / 4, 256, 0, stream>>>(rowptr, deg, esrc, au, av, h, agg, N);

    ff_kernel<<<row_blocks, 512, 0, stream>>>(agg, w1_b, b1, w2_b, b2, (float*)d_out, N);
}